// Round 2
// baseline (218.806 us; speedup 1.0000x reference)
//
#include <hip/hip_runtime.h>

// Combine: out[b,:] = branches[argmax(gate[b,:4])][b,:]
// B=4096 rows, D=4096 fp32/row, N=4 branches. Memory-bound select-copy.
//
// v3: streaming pipeline. v1 (serial, VGPR=8) == v2 (batched, VGPR=24) == 42us
// proved MLP/VGPR/nt-store are not the limiter. Remaining delta vs the
// 6.3 TB/s copy ubench: one-cohort read-burst-then-write-burst structure.
// Now: 1024 blocks x 4 rows, gate selects hoisted, 2-row-deep software
// pipeline (L0 L1 S0 L2 S1 L3 S2 S3) with all-distinct registers so the
// compiler emits counted vmcnt(N) and loads of row r+1 overlap stores of
// row r -> sustained 50/50 R/W mix machine-wide.

#define B 4096
#define D 4096
#define ROWS 4
#define NBLK (B / ROWS)  // 1024 blocks = 4 blocks/CU, 16 waves/CU

typedef float f32x4 __attribute__((ext_vector_type(4)));

__global__ __launch_bounds__(256) void combine_kernel(
    const float* __restrict__ b0, const float* __restrict__ b1,
    const float* __restrict__ b2, const float* __restrict__ b3,
    const float* __restrict__ gate, float* __restrict__ out) {

    const int t = threadIdx.x;
    const int row0 = blockIdx.x * ROWS;

    // Resolve all 4 source-row pointers up front (4 independent 16B gate
    // loads issued back-to-back; strict > matches jnp.argmax tie-break;
    // selection is wave-uniform per row -> no divergence).
    const f32x4* src[ROWS];
    f32x4* dst[ROWS];
    #pragma unroll
    for (int r = 0; r < ROWS; ++r) {
        const int row = row0 + r;
        f32x4 g = ((const f32x4*)gate)[row];
        int idx = 0;
        float best = g.x;
        if (g.y > best) { best = g.y; idx = 1; }
        if (g.z > best) { best = g.z; idx = 2; }
        if (g.w > best) { best = g.w; idx = 3; }
        const float* p = (idx == 0) ? b0 : (idx == 1) ? b1 : (idx == 2) ? b2 : b3;
        src[r] = (const f32x4*)(p + (size_t)row * D);
        dst[r] = (f32x4*)(out + (size_t)row * D);
    }

    // 1024 float4 per row / 256 threads = 4 float4/thread/row.
    // All-distinct registers: no WAR hazards between a row's stores and the
    // next row's loads, so no forced vmcnt drains inside the pipeline.
    f32x4 a0, a1, a2, a3;   // row 0
    f32x4 c0, c1, c2, c3;   // row 1
    f32x4 e0, e1, e2, e3;   // row 2
    f32x4 h0, h1, h2, h3;   // row 3

#define LOADROW(v0, v1, v2, v3, r)                                          \
    do {                                                                    \
        const f32x4* s_ = src[r];                                           \
        v0 = s_[t];       v1 = s_[t + 256];                                 \
        v2 = s_[t + 512]; v3 = s_[t + 768];                                 \
    } while (0)

#define STOREROW(v0, v1, v2, v3, r)                                         \
    do {                                                                    \
        f32x4* d_ = dst[r];                                                 \
        __builtin_nontemporal_store(v0, &d_[t]);                            \
        __builtin_nontemporal_store(v1, &d_[t + 256]);                      \
        __builtin_nontemporal_store(v2, &d_[t + 512]);                      \
        __builtin_nontemporal_store(v3, &d_[t + 768]);                      \
    } while (0)

    // 2-row-deep pipeline: stores of row r overlap loads of row r+1.
    LOADROW(a0, a1, a2, a3, 0);
    LOADROW(c0, c1, c2, c3, 1);
    STOREROW(a0, a1, a2, a3, 0);
    LOADROW(e0, e1, e2, e3, 2);
    STOREROW(c0, c1, c2, c3, 1);
    LOADROW(h0, h1, h2, h3, 3);
    STOREROW(e0, e1, e2, e3, 2);
    STOREROW(h0, h1, h2, h3, 3);

#undef LOADROW
#undef STOREROW
}

extern "C" void kernel_launch(void* const* d_in, const int* in_sizes, int n_in,
                              void* d_out, int out_size, void* d_ws, size_t ws_size,
                              hipStream_t stream) {
    const float* b0   = (const float*)d_in[0];
    const float* b1   = (const float*)d_in[1];
    const float* b2   = (const float*)d_in[2];
    const float* b3   = (const float*)d_in[3];
    const float* gate = (const float*)d_in[4];
    float* out = (float*)d_out;

    combine_kernel<<<NBLK, 256, 0, stream>>>(b0, b1, b2, b3, gate, out);
}

// Round 4
// 215.577 us; speedup vs baseline: 1.0150x; 1.0150x over previous
//
#include <hip/hip_runtime.h>

// Combine: out[b,:] = branches[argmax(gate[b,:4])][b,:]
// B=4096 rows, D=4096 fp32/row, N=4 branches. Memory-bound select-copy.
//
// v4 (resubmit — R3 failed on container acquisition, kernel never ran).
// v1 (serial burst), v2 (batched burst), v3 (pipelined burst) all pinned at
// 42-44us across occupancy 24-60% => no per-CU/per-wave resource is the
// limiter. Last structural delta vs the 6.3 TB/s float4-copy ubench is the
// kernel SHAPE: flat grid-stride copy, 100% occupancy, continuous
// interleaved load/store issue over a linear index space.
// Because each branch is a full [B,D] array, the select-copy is just
//   out4[i] = base4[i],  base chosen by gate[i>>10]
// on a flat float4 index. i>>10 is exactly wave-uniform (1024 float4/row,
// waves 64-aligned) -> gate load is one broadcast L1 transaction per wave,
// and gate (64 KB) is fully cache-resident.

#define B 4096
#define D 4096
#define NV4 (B * D / 4)            // 4,194,304 float4s
#define THREADS 256
#define BLOCKS 2048                // 8 blocks/CU -> 32 waves/CU (100% occ)
#define STRIDE (THREADS * BLOCKS)  // 524,288 threads
#define ITERS (NV4 / STRIDE)       // 8, exact (no tail)

typedef float f32x4 __attribute__((ext_vector_type(4)));

__global__ __launch_bounds__(THREADS) void combine_kernel(
    const float* __restrict__ b0, const float* __restrict__ b1,
    const float* __restrict__ b2, const float* __restrict__ b3,
    const float* __restrict__ gate, float* __restrict__ out) {

    const f32x4* __restrict__ g4 = (const f32x4*)gate;
    const f32x4* __restrict__ s0 = (const f32x4*)b0;
    const f32x4* __restrict__ s1 = (const f32x4*)b1;
    const f32x4* __restrict__ s2 = (const f32x4*)b2;
    const f32x4* __restrict__ s3 = (const f32x4*)b3;
    f32x4* __restrict__ d4 = (f32x4*)out;

    size_t idx = (size_t)blockIdx.x * THREADS + threadIdx.x;

    #pragma unroll
    for (int i = 0; i < ITERS; ++i, idx += STRIDE) {
        const int row = (int)(idx >> 10);  // D/4 = 1024 float4 per row

        // First-occurrence argmax (strict >) matches jnp.argmax tie-break.
        f32x4 g = g4[row];
        int sel = 0;
        float best = g.x;
        if (g.y > best) { best = g.y; sel = 1; }
        if (g.z > best) { best = g.z; sel = 2; }
        if (g.w > best) { best = g.w; sel = 3; }

        const f32x4* src = (sel == 0) ? s0
                         : (sel == 1) ? s1
                         : (sel == 2) ? s2
                         : s3;

        d4[idx] = src[idx];
    }
}

extern "C" void kernel_launch(void* const* d_in, const int* in_sizes, int n_in,
                              void* d_out, int out_size, void* d_ws, size_t ws_size,
                              hipStream_t stream) {
    const float* b0   = (const float*)d_in[0];
    const float* b1   = (const float*)d_in[1];
    const float* b2   = (const float*)d_in[2];
    const float* b3   = (const float*)d_in[3];
    const float* gate = (const float*)d_in[4];
    float* out = (float*)d_out;

    combine_kernel<<<BLOCKS, THREADS, 0, stream>>>(b0, b1, b2, b3, gate, out);
}

// Round 5
// 205.656 us; speedup vs baseline: 1.0639x; 1.0482x over previous
//
#include <hip/hip_runtime.h>

// Combine: out[b,:] = branches[argmax(gate[b,:4])][b,:]
// B=4096 rows, D=4096 fp32/row, N=4 branches. Memory-bound select-copy.
//
// v5: cache-policy probe. v1-v4 (4 different structures, occ 24-63%) all pin
// at 41-44us with NO saturated counter: VALUBusy<5%, VMEM issue ~1% of cap,
// L2 3.2/34.5 TB/s, HBM counted 2.4 TB/s while the harness's own
// fillBufferAligned sustains 6.63 TB/s (262MB/40.4us) in the same session.
// Last HIP-visible lever: the read stream (zero reuse) allocates in L2/L3
// and contends with the 262MB of fill-dirty lines the harness re-poisons
// every iteration (FETCH pinned at exactly ~half the read set in every
// version). v5 = v4 flat grid-stride + nontemporal LOADS on branch data
// (gate keeps normal caching: cross-wave reuse) + nontemporal stores.
// Outcomes: dur down => cache interference was the wall; dur flat+FETCH up
// => HBM has headroom, wall is elsewhere; dur up+FETCH up => counted-BW
// ceiling is real, declare roofline with that arithmetic.

#define B 4096
#define D 4096
#define NV4 (B * D / 4)            // 4,194,304 float4s
#define THREADS 256
#define BLOCKS 2048                // 8 blocks/CU -> 32 waves/CU
#define STRIDE (THREADS * BLOCKS)  // 524,288 threads
#define ITERS (NV4 / STRIDE)       // 8, exact (no tail)

typedef float f32x4 __attribute__((ext_vector_type(4)));

__global__ __launch_bounds__(THREADS) void combine_kernel(
    const float* __restrict__ b0, const float* __restrict__ b1,
    const float* __restrict__ b2, const float* __restrict__ b3,
    const float* __restrict__ gate, float* __restrict__ out) {

    const f32x4* __restrict__ g4 = (const f32x4*)gate;
    const f32x4* __restrict__ s0 = (const f32x4*)b0;
    const f32x4* __restrict__ s1 = (const f32x4*)b1;
    const f32x4* __restrict__ s2 = (const f32x4*)b2;
    const f32x4* __restrict__ s3 = (const f32x4*)b3;
    f32x4* __restrict__ d4 = (f32x4*)out;

    size_t idx = (size_t)blockIdx.x * THREADS + threadIdx.x;

    #pragma unroll
    for (int i = 0; i < ITERS; ++i, idx += STRIDE) {
        const int row = (int)(idx >> 10);  // D/4 = 1024 float4 per row

        // First-occurrence argmax (strict >) matches jnp.argmax tie-break.
        // Gate load stays normally-cached (reused by all waves of the row).
        f32x4 g = g4[row];
        int sel = 0;
        float best = g.x;
        if (g.y > best) { best = g.y; sel = 1; }
        if (g.z > best) { best = g.z; sel = 2; }
        if (g.w > best) { best = g.w; sel = 3; }

        const f32x4* src = (sel == 0) ? s0
                         : (sel == 1) ? s1
                         : (sel == 2) ? s2
                         : s3;

        // Zero-reuse streaming data: bypass cache allocation on both sides.
        f32x4 v = __builtin_nontemporal_load(&src[idx]);
        __builtin_nontemporal_store(v, &d4[idx]);
    }
}

extern "C" void kernel_launch(void* const* d_in, const int* in_sizes, int n_in,
                              void* d_out, int out_size, void* d_ws, size_t ws_size,
                              hipStream_t stream) {
    const float* b0   = (const float*)d_in[0];
    const float* b1   = (const float*)d_in[1];
    const float* b2   = (const float*)d_in[2];
    const float* b3   = (const float*)d_in[3];
    const float* gate = (const float*)d_in[4];
    float* out = (float*)d_out;

    combine_kernel<<<BLOCKS, THREADS, 0, stream>>>(b0, b1, b2, b3, gate, out);
}